// Round 9
// baseline (24520.573 us; speedup 1.0000x reference)
//
#include <hip/hip_runtime.h>
#include <cstdint>
#include <cstddef>

// Decoder (LFADS-like): B=512, T=200.
// Persistent kernel v4 — per-XCD islands (r8-proven sync) + memory-level
// parallelism: r8 was latency-bound streaming weights at 92 GB/s/XCD
// (traffic/rate == runtime). v4 raises outstanding bytes:
//   * NBLK 512 (2 blocks/CU, 8 waves/CU)
//   * 4 weight streams per wave (1 shared A-load + 4 B-loads + 4 MFMA/kt)
//   * barrier arrival split over 4 sub-counters + root per XCD (all sc0
//     atomics, r8-proven; polls via atomic-add-0 = L2-fresh).
// Precomposed weights:
//   W'  = com_W @ gen_K[:32]    (co_mean folded into generator GEMM)
//   W'' = fac_Wn @ con_K[128:]  (factor path folded into controller GEMM;
//                                fac_Wn columns appended -> facs for free)

#define B_   512
#define T_   200
#define CI_  128
#define EXT_ 8
#define GEN_ 800
#define CON_ 400
#define CO_  32
#define FAC_ 128
#define NBLK 512

typedef __attribute__((ext_vector_type(8))) short short8;
typedef __attribute__((ext_vector_type(4))) float f32x4;
typedef __attribute__((ext_vector_type(4))) unsigned short us4;
typedef unsigned short us;

// sync-cell layout in gs (u32 indices, 256 B apart => one XCD per line):
#define ARR_(g,c) (((g)*4+(c))*64)
#define FLAG_(g)  (2048 + (g)*64)
#define ROOT_(g)  (2560 + (g)*64)
#define SLOT_(g)  (3584 + (g)*64)
#define AREG_     4096
#define GSYNC_N   4352

__device__ __forceinline__ us f2bf(float f) {
  unsigned int u = __float_as_uint(f);
  u += 0x7FFFu + ((u >> 16) & 1u);   // RNE
  return (us)(u >> 16);
}
__device__ __forceinline__ unsigned pk2(float a, float b) {
  return (unsigned)f2bf(a) | ((unsigned)f2bf(b) << 16);
}
__device__ __forceinline__ float sigm(float x) { return 1.0f / (1.0f + __expf(-x)); }

// ---- sc0 (XCD-L2-coherent) primitives -------------------------------------
__device__ __forceinline__ void st128_sc0(void* p, f32x4 v) {
  asm volatile("global_store_dwordx4 %0, %1, off sc0" :: "v"(p), "v"(v) : "memory");
}
__device__ __forceinline__ void st64_sc0(void* p, unsigned lo, unsigned hi) {
  unsigned long long v = (unsigned long long)lo | ((unsigned long long)hi << 32);
  asm volatile("global_store_dwordx2 %0, %1, off sc0" :: "v"(p), "v"(v) : "memory");
}
__device__ __forceinline__ void st32_sc0(void* p, unsigned v) {
  asm volatile("global_store_dword %0, %1, off sc0" :: "v"(p), "v"(v) : "memory");
}
__device__ __forceinline__ unsigned atom_add_sc0(void* p, unsigned d) {
  unsigned old;
  asm volatile("global_atomic_add %0, %1, %2, off sc0\n\ts_waitcnt vmcnt(0)"
               : "=v"(old) : "v"(p), "v"(d) : "memory");
  return old;
}
// L2-fresh read: atomic add of 0 (atomics execute at the L2, never hit L0)
__device__ __forceinline__ unsigned ld_l2(void* p) { return atom_add_sc0(p, 0u); }

// ---------------- setup kernels ----------------

__global__ void k_facnorm(const float* __restrict__ facW, float* __restrict__ facWn) {
  int j = blockIdx.x;
  int l = threadIdx.x;
  float s = 0.f;
  for (int k = l; k < GEN_; k += 64) { float v = facW[(size_t)k*FAC_ + j]; s += v*v; }
  #pragma unroll
  for (int off = 32; off > 0; off >>= 1) s += __shfl_down(s, off, 64);
  float inv = 1.0f / sqrtf(__shfl(s, 0, 64));
  for (int k = l; k < GEN_; k += 64) facWn[(size_t)k*FAC_ + j] = facW[(size_t)k*FAC_ + j] * inv;
}

__global__ void k_w2(const float* __restrict__ facWn, const float* __restrict__ conK,
                     float* __restrict__ tmp2) {
  int n = blockIdx.x*256 + threadIdx.x; if (n >= 1200) return;
  int kp = blockIdx.y;
  const float* fr = facWn + (size_t)kp*FAC_;
  float s = 0.f;
  for (int j = 0; j < FAC_; ++j) s = fmaf(fr[j], conK[(size_t)(CI_+j)*1200 + n], s);
  tmp2[(size_t)kp*1200 + n] = s;
}

__global__ void k_w1(const float* __restrict__ comW, const float* __restrict__ genK,
                     float* __restrict__ tmp1) {
  int n = blockIdx.x*256 + threadIdx.x; if (n >= 2400) return;
  int k = blockIdx.y;
  const float* cr = comW + (size_t)k*CO_;
  float s = 0.f;
  for (int j = 0; j < CO_; ++j) s = fmaf(cr[j], genK[(size_t)j*2400 + n], s);
  tmp1[(size_t)k*2400 + n] = s;
}

__global__ void k_cvt(const float* __restrict__ ci, const float* __restrict__ ext,
                      us* __restrict__ cib, us* __restrict__ extb) {
  const long n1 = (long)B_*T_*CI_/4;
  const long n2 = (long)B_*T_*EXT_/4;
  for (long i = blockIdx.x*(long)blockDim.x + threadIdx.x; i < n1+n2;
       i += (long)gridDim.x*blockDim.x) {
    if (i < n1) {
      float4 f = reinterpret_cast<const float4*>(ci)[i];
      us4 u; u.x=f2bf(f.x); u.y=f2bf(f.y); u.z=f2bf(f.z); u.w=f2bf(f.w);
      reinterpret_cast<us4*>(cib)[i] = u;
    } else {
      long k = i - n1;
      float4 f = reinterpret_cast<const float4*>(ext)[k];
      us4 u; u.x=f2bf(f.x); u.y=f2bf(f.y); u.z=f2bf(f.z); u.w=f2bf(f.w);
      reinterpret_cast<us4*>(extb)[k] = u;
    }
  }
}

__global__ void k_init(const float* __restrict__ conh0, const float* __restrict__ geninit,
                       const float* __restrict__ conb, const float* __restrict__ genb,
                       const float* __restrict__ comb, const float* __restrict__ genK,
                       float* __restrict__ bczr, float* __restrict__ bgzr,
                       float* __restrict__ conh, us* __restrict__ agzr,
                       float* __restrict__ genh, us* __restrict__ genhb,
                       us* __restrict__ achh,
                       us* __restrict__ zbuf, unsigned* __restrict__ gs) {
  const long R0=1344, R1=2432, R2=(long)B_*CON_, R3=(long)B_*CON_,
             R4=(long)B_*GEN_, R5=(long)B_*GEN_, R6=(long)B_*416, R7=64, R8=GSYNC_N;
  const long total = R0+R1+R2+R3+R4+R5+R6+R7+R8;
  for (long idx = blockIdx.x*(long)blockDim.x + threadIdx.x; idx < total;
       idx += (long)gridDim.x*blockDim.x) {
    long i = idx;
    if (i < R0) { bczr[i] = (i < 1200) ? conb[i] : 0.f; continue; }
    i -= R0;
    if (i < R1) {
      float s = 0.f;
      if (i < 2400) { s = genb[i]; for (int j=0;j<32;++j) s = fmaf(comb[j], genK[(size_t)j*2400 + i], s); }
      bgzr[i] = s; continue;
    }
    i -= R1;
    if (i < R2) { conh[i] = conh0[i % CON_]; continue; }
    i -= R2;
    if (i < R3) { agzr[i] = f2bf(conh0[i % CON_]); continue; }
    i -= R3;
    if (i < R4) { genh[i] = geninit[i]; continue; }
    i -= R4;
    if (i < R5) { genhb[i] = f2bf(geninit[i]); continue; }
    i -= R5;
    if (i < R6) { achh[i] = 0; continue; }
    i -= R6;
    if (i < R7) { zbuf[i] = 0; continue; }
    i -= R7;
    gs[i] = 0;
  }
}

// build transposed bf16 weights: dst[n][k] = fetch(k, n)
struct BTArgs {
  int mode, K;
  const float* conK; const float* conR; const float* genK; const float* genR;
  const float* facWn; const float* tmp1; const float* tmp2;
  us* dst;
};

__device__ __forceinline__ float bt_fetch(const BTArgs& a, int k, int n) {
  switch (a.mode) {
    case 0: // W_czr^T: K=1344 (ci128|gen800|con416), N=1408 (z400|r400|xh400|fac128|pad)
      if (n < 1200) {
        if (k < 128)  return a.conK[(size_t)k*1200 + n];
        if (k < 928)  return a.tmp2[(size_t)(k-128)*1200 + n];
        if (k < 1328) return (n < 800) ? a.conR[(size_t)(k-928)*1200 + n] : 0.f;
        return 0.f;
      }
      if (n < 1328) return (k >= 128 && k < 928) ? a.facWn[(size_t)(k-128)*FAC_ + (n-1200)] : 0.f;
      return 0.f;
    case 1: // W_chh^T: con_R[:,800:1200]
      return (k < 400 && n < 400) ? a.conR[(size_t)k*1200 + 800 + n] : 0.f;
    case 2: // W_gzr^T: K=1216 (conh400|ext8|pad8|genh800), N=2432 (z800|r800|xh800|pad)
      if (n >= 2400) return 0.f;
      if (k < 400)  return a.tmp1[(size_t)k*2400 + n];
      if (k < 408)  return a.genK[(size_t)(32 + k - 400)*2400 + n];
      if (k < 416)  return 0.f;
      if (k < 1216) return (n < 1600) ? a.genR[(size_t)(k-416)*2400 + n] : 0.f;
      return 0.f;
    case 3: // W_ghh^T: gen_R[:,1600:2400]
      return (n < 800 && k < 800) ? a.genR[(size_t)k*2400 + 1600 + n] : 0.f;
    default: // fac_Wn^T [192 pad][800]
      return (k < 800 && n < 128) ? a.facWn[(size_t)k*FAC_ + n] : 0.f;
  }
}

__global__ __launch_bounds__(256) void k_buildT(BTArgs a) {
  __shared__ float tile[64][65];
  int k0 = blockIdx.x*64, n0 = blockIdx.y*64;
  int tid = threadIdx.x;
  int rr = tid >> 2, cc = (tid & 3) * 16;
  #pragma unroll 4
  for (int i = 0; i < 16; ++i) tile[rr][cc+i] = bt_fetch(a, k0+rr, n0+cc+i);
  __syncthreads();
  int n = n0 + rr;
  if (k0 + cc < a.K) {
    short8 v0, v1;
    #pragma unroll
    for (int i = 0; i < 8; ++i) v0[i] = (short)f2bf(tile[cc+i][rr]);
    #pragma unroll
    for (int i = 0; i < 8; ++i) v1[i] = (short)f2bf(tile[cc+8+i][rr]);
    *reinterpret_cast<short8*>(&a.dst[(size_t)n*a.K + k0 + cc])     = v0;
    *reinterpret_cast<short8*>(&a.dst[(size_t)n*a.K + k0 + cc + 8]) = v1;
  }
}

// ---------------- persistent decoder ----------------

struct PA {
  const us* cib; const us* extb;
  const us* wczr; const us* wchh; const us* wgzr; const us* wghh; const us* wfac;
  const float* bczr; const float* bgzr;
  float* zcon; float* xhcon; float* zgen; float* xhgen;
  float* conh; float* genh;
  us* genhb; us* agzr; us* achh; us* aghh;
  const us* zbuf;
  float* out;
  unsigned* gs;
};

enum { S_CZR=0, S_CHH=1, S_GZR=2, S_GHH=3, S_FAC=4 };

// per-XCD barrier: 4 arrive sub-counters + root (sc0 atomics, local L2),
// flag set by last root arrival; polls via atomic-add-0 (L2-fresh).
__device__ __forceinline__ void gbar(unsigned* gs, int g, int slot, unsigned cnt, unsigned ep) {
  asm volatile("s_waitcnt vmcnt(0)" ::: "memory");   // this wave's stores in L2
  __syncthreads();                                   // all waves drained
  if (threadIdx.x == 0) {
    const unsigned c = (unsigned)slot & 3u;
    const unsigned n_c = (cnt + 3u - c) >> 2;        // #slots with slot&3==c
    unsigned old = atom_add_sc0(&gs[ARR_(g, c)], 1u);
    if (old + 1u >= n_c * ep) {                      // last of this sub-group
      const unsigned nsub = cnt < 4u ? cnt : 4u;
      unsigned r = atom_add_sc0(&gs[ROOT_(g)], 1u);
      if (r + 1u >= nsub * ep) st32_sc0(&gs[FLAG_(g)], ep);
    }
    long guard = 0;
    for (;;) {
      unsigned v = ld_l2(&gs[FLAG_(g)]);
      if ((int)(v - ep) >= 0) break;
      if (++guard > 300000L) break;                  // slow-fail, never hang
      __builtin_amdgcn_s_sleep(1);
    }
  }
  __syncthreads();
  asm volatile("buffer_inv sc0" ::: "memory");       // L0-only invalidate
}

template<int STAGE>
__device__ __forceinline__ void epi(const PA& a, int t, int bb, int c0, f32x4 v) {
  if constexpr (STAGE == S_CZR) {
    if (c0 < 400) {
      float4 b = *reinterpret_cast<const float4*>(&a.bczr[c0]);
      f32x4 z = { sigm(v[0]+b.x), sigm(v[1]+b.y), sigm(v[2]+b.z), sigm(v[3]+b.w) };
      st128_sc0(&a.zcon[(size_t)bb*CON_ + c0], z);
    } else if (c0 < 800) {
      float4 b = *reinterpret_cast<const float4*>(&a.bczr[c0]);
      int u0 = c0 - 400;
      float4 hp = *reinterpret_cast<const float4*>(&a.conh[(size_t)bb*CON_ + u0]);
      float r0 = sigm(v[0]+b.x)*hp.x, r1 = sigm(v[1]+b.y)*hp.y;
      float r2 = sigm(v[2]+b.z)*hp.z, r3 = sigm(v[3]+b.w)*hp.w;
      st64_sc0(&a.achh[(size_t)bb*416 + u0], pk2(r0,r1), pk2(r2,r3));
    } else if (c0 < 1200) {
      float4 b = *reinterpret_cast<const float4*>(&a.bczr[c0]);
      f32x4 x = { v[0]+b.x, v[1]+b.y, v[2]+b.z, v[3]+b.w };
      st128_sc0(&a.xhcon[(size_t)bb*CON_ + (c0-800)], x);
    } else if (c0 < 1328) {
      if (t > 0) {
        float4* o = reinterpret_cast<float4*>(&a.out[((size_t)bb*T_ + (t-1))*FAC_ + (c0-1200)]);
        *o = make_float4(v[0], v[1], v[2], v[3]);
      }
    }
  } else if constexpr (STAGE == S_CHH) {
    if (c0 < 400) {
      float4 xh = *reinterpret_cast<const float4*>(&a.xhcon[(size_t)bb*CON_ + c0]);
      float4 zz = *reinterpret_cast<const float4*>(&a.zcon [(size_t)bb*CON_ + c0]);
      float4 hp = *reinterpret_cast<const float4*>(&a.conh [(size_t)bb*CON_ + c0]);
      float h[4]; float xs[4] = {xh.x,xh.y,xh.z,xh.w};
      float zs[4] = {zz.x,zz.y,zz.z,zz.w}; float hs[4] = {hp.x,hp.y,hp.z,hp.w};
      #pragma unroll
      for (int j=0;j<4;++j) {
        float hh = tanhf(v[j] + xs[j]);
        float hn = zs[j]*hs[j] + (1.f - zs[j])*hh;
        h[j] = fminf(fmaxf(hn, -5.f), 5.f);
      }
      st128_sc0(&a.conh[(size_t)bb*CON_ + c0], (f32x4){h[0],h[1],h[2],h[3]});
      st64_sc0(&a.agzr[(size_t)bb*CON_ + c0], pk2(h[0],h[1]), pk2(h[2],h[3]));
    }
  } else if constexpr (STAGE == S_GZR) {
    if (c0 < 800) {
      float4 b = *reinterpret_cast<const float4*>(&a.bgzr[c0]);
      f32x4 z = { sigm(v[0]+b.x), sigm(v[1]+b.y), sigm(v[2]+b.z), sigm(v[3]+b.w) };
      st128_sc0(&a.zgen[(size_t)bb*GEN_ + c0], z);
    } else if (c0 < 1600) {
      float4 b = *reinterpret_cast<const float4*>(&a.bgzr[c0]);
      int u0 = c0 - 800;
      float4 hp = *reinterpret_cast<const float4*>(&a.genh[(size_t)bb*GEN_ + u0]);
      float r0 = sigm(v[0]+b.x)*hp.x, r1 = sigm(v[1]+b.y)*hp.y;
      float r2 = sigm(v[2]+b.z)*hp.z, r3 = sigm(v[3]+b.w)*hp.w;
      st64_sc0(&a.aghh[(size_t)bb*GEN_ + u0], pk2(r0,r1), pk2(r2,r3));
    } else if (c0 < 2400) {
      float4 b = *reinterpret_cast<const float4*>(&a.bgzr[c0]);
      f32x4 x = { v[0]+b.x, v[1]+b.y, v[2]+b.z, v[3]+b.w };
      st128_sc0(&a.xhgen[(size_t)bb*GEN_ + (c0-1600)], x);
    }
  } else if constexpr (STAGE == S_GHH) {
    if (c0 < 800) {
      float4 xh = *reinterpret_cast<const float4*>(&a.xhgen[(size_t)bb*GEN_ + c0]);
      float4 zz = *reinterpret_cast<const float4*>(&a.zgen [(size_t)bb*GEN_ + c0]);
      float4 hp = *reinterpret_cast<const float4*>(&a.genh [(size_t)bb*GEN_ + c0]);
      float h[4]; float xs[4] = {xh.x,xh.y,xh.z,xh.w};
      float zs[4] = {zz.x,zz.y,zz.z,zz.w}; float hs[4] = {hp.x,hp.y,hp.z,hp.w};
      #pragma unroll
      for (int j=0;j<4;++j) {
        float hh = tanhf(v[j] + xs[j]);
        float hn = zs[j]*hs[j] + (1.f - zs[j])*hh;
        h[j] = fminf(fmaxf(hn, -5.f), 5.f);
      }
      st128_sc0(&a.genh[(size_t)bb*GEN_ + c0], (f32x4){h[0],h[1],h[2],h[3]});
      st64_sc0(&a.genhb[(size_t)bb*GEN_ + c0], pk2(h[0],h[1]), pk2(h[2],h[3]));
    }
  } else { // S_FAC
    if (c0 < 128) {
      float4* o = reinterpret_cast<float4*>(&a.out[((size_t)bb*T_ + (T_-1))*FAC_ + c0]);
      *o = make_float4(v[0], v[1], v[2], v[3]);
    }
  }
}

template<int STAGE, int K, int F>
__device__ __forceinline__ void do_stage(const PA& a, int t, int g, int slot, int cnt) {
  const int lane = threadIdx.x & 63, wid = threadIdx.x >> 6;
  int base = (int)((long)slot * F / cnt);
  int end  = (int)((long)(slot+1) * F / cnt);
  if (end > F) end = F;
  if (base >= end) return;

  const us* warr =
      STAGE == S_CZR ? a.wczr : STAGE == S_CHH ? a.wchh :
      STAGE == S_GZR ? a.wgzr : STAGE == S_GHH ? a.wghh : a.wfac;

  const int l15 = lane & 15, ko = (lane >> 4) * 8;
  const int bb = g*64 + wid*16 + l15;    // this lane's batch row (D col)

  const us *A0 = nullptr, *A1 = nullptr, *A2 = nullptr;
  if constexpr (STAGE == S_CZR) {
    A0 = a.cib   + ((size_t)bb*T_ + t)*CI_;
    A1 = a.genhb + (size_t)bb*GEN_ - 128;
    A2 = a.agzr  + (size_t)bb*CON_ - 928;
  } else if constexpr (STAGE == S_CHH) {
    A0 = a.achh + (size_t)bb*416;
  } else if constexpr (STAGE == S_GZR) {
    A0 = a.agzr  + (size_t)bb*CON_;
    A1 = a.extb  + ((size_t)bb*T_ + t)*EXT_ - 400;
    A2 = a.genhb + (size_t)bb*GEN_ - 416;
  } else if constexpr (STAGE == S_GHH) {
    A0 = a.aghh + (size_t)bb*GEN_;
  } else {
    A0 = a.genhb + (size_t)bb*GEN_;
  }

  // 4 concurrent weight streams per wave (shared A-stream)
  for (int nf = base; nf < end; nf += 4) {
    const us* wp[4];
    #pragma unroll
    for (int j = 0; j < 4; ++j) {
      const int f = (nf + j < end) ? nf + j : nf;    // safe duplicate for tail
      wp[j] = warr + (size_t)(f*16 + l15)*K + ko;
    }
    f32x4 acc[4];
    #pragma unroll
    for (int j = 0; j < 4; ++j) acc[j] = (f32x4){0.f,0.f,0.f,0.f};

    #pragma unroll 4
    for (int kt = 0; kt < K/32; ++kt) {
      const int k0 = kt*32 + ko;
      const us* p;
      if constexpr (STAGE == S_CZR) {
        p = k0 < 128 ? A0 + k0 : k0 < 928 ? A1 + k0
          : k0 < 1328 ? A2 + k0 : a.zbuf;
      } else if constexpr (STAGE == S_GZR) {
        p = k0 < 400 ? A0 + k0 : k0 < 408 ? A1 + k0
          : k0 < 416 ? a.zbuf : A2 + k0;
      } else {
        p = A0 + k0;
      }
      short8 av = *reinterpret_cast<const short8*>(p);
      short8 bv0 = *reinterpret_cast<const short8*>(wp[0] + kt*32);
      short8 bv1 = *reinterpret_cast<const short8*>(wp[1] + kt*32);
      short8 bv2 = *reinterpret_cast<const short8*>(wp[2] + kt*32);
      short8 bv3 = *reinterpret_cast<const short8*>(wp[3] + kt*32);
      acc[0] = __builtin_amdgcn_mfma_f32_16x16x32_bf16(bv0, av, acc[0], 0,0,0);
      acc[1] = __builtin_amdgcn_mfma_f32_16x16x32_bf16(bv1, av, acc[1], 0,0,0);
      acc[2] = __builtin_amdgcn_mfma_f32_16x16x32_bf16(bv2, av, acc[2], 0,0,0);
      acc[3] = __builtin_amdgcn_mfma_f32_16x16x32_bf16(bv3, av, acc[3], 0,0,0);
    }
    const int cq = (lane >> 4) * 4;
    #pragma unroll
    for (int j = 0; j < 4; ++j)
      if (nf + j < end) epi<STAGE>(a, t, bb, (nf+j)*16 + cq, acc[j]);
  }
}

__global__ __launch_bounds__(256) void decoder_persist(PA a) {
  const int tid = threadIdx.x;
  unsigned xcc;
  asm("s_getreg_b32 %0, hwreg(HW_REG_XCC_ID)" : "=s"(xcc));
  const int g = (int)(xcc & 7u);

  __shared__ int s_slot, s_cnt;
  if (tid == 0) {
    s_slot = (int)atom_add_sc0(&a.gs[SLOT_(g)], 1u);
  }
  __syncthreads();
  if (tid == 0) {
    // one-time global registration barrier (relaxed agent scope, r4-proven)
    __hip_atomic_fetch_add(&a.gs[AREG_], 1u, __ATOMIC_RELAXED, __HIP_MEMORY_SCOPE_AGENT);
    long guard = 0;
    for (;;) {
      unsigned v = __hip_atomic_load(&a.gs[AREG_], __ATOMIC_RELAXED, __HIP_MEMORY_SCOPE_AGENT);
      if (v >= (unsigned)NBLK) break;
      if (++guard > 20000000L) break;
      __builtin_amdgcn_s_sleep(1);
    }
    int c = (int)ld_l2(&a.gs[SLOT_(g)]);   // L2-fresh group count
    s_cnt = c < 1 ? 1 : c;
  }
  __syncthreads();
  const int slot = s_slot;
  const unsigned cnt = (unsigned)s_cnt;
  asm volatile("buffer_inv sc0" ::: "memory");

  unsigned ep = 0;
  for (int t = 0; t < T_; ++t) {
    do_stage<S_CZR, 1344,  83>(a, t, g, slot, (int)cnt);  gbar(a.gs, g, slot, cnt, ++ep);
    do_stage<S_CHH,  416,  25>(a, t, g, slot, (int)cnt);  gbar(a.gs, g, slot, cnt, ++ep);
    do_stage<S_GZR, 1216, 150>(a, t, g, slot, (int)cnt);  gbar(a.gs, g, slot, cnt, ++ep);
    do_stage<S_GHH,  800,  50>(a, t, g, slot, (int)cnt);  gbar(a.gs, g, slot, cnt, ++ep);
  }
  do_stage<S_FAC, 800, 8>(a, T_-1, g, slot, (int)cnt);
}

// ---------------- host ----------------

extern "C" void kernel_launch(void* const* d_in, const int* in_sizes, int n_in,
                              void* d_out, int out_size, void* d_ws, size_t ws_size,
                              hipStream_t stream) {
  const float* ci      = (const float*)d_in[0];
  const float* ext     = (const float*)d_in[1];
  const float* geninit = (const float*)d_in[2];
  const float* conh0   = (const float*)d_in[3];
  const float* conK    = (const float*)d_in[4];
  const float* conR    = (const float*)d_in[5];
  const float* conb    = (const float*)d_in[6];
  const float* comW    = (const float*)d_in[7];
  const float* comb    = (const float*)d_in[8];
  const float* genK    = (const float*)d_in[11];
  const float* genR    = (const float*)d_in[12];
  const float* genb    = (const float*)d_in[13];
  const float* facW    = (const float*)d_in[14];
  float* out = (float*)d_out;

  char* ws = (char*)d_ws;
  size_t off = 0;
  auto alloc = [&](size_t bytes) -> void* {
    void* p = ws + off;
    off = (off + bytes + 255) & ~(size_t)255;
    return p;
  };
  us* wczr  = (us*)alloc(1408UL*1344*2);
  us* wchh  = (us*)alloc(512UL*416*2);
  us* wgzr  = (us*)alloc(2432UL*1216*2);
  us* wghh  = (us*)alloc(896UL*800*2);
  us* wfac  = (us*)alloc(192UL*800*2);
  float* facWn = (float*)alloc(800UL*128*4);
  float* tmp2  = (float*)alloc(800UL*1200*4);
  float* tmp1  = (float*)alloc(400UL*2400*4);
  float* bczr  = (float*)alloc(1344UL*4);
  float* bgzr  = (float*)alloc(2432UL*4);
  float* conh  = (float*)alloc((size_t)B_*CON_*4);
  float* genh  = (float*)alloc((size_t)B_*GEN_*4);
  us* genhb = (us*)alloc((size_t)B_*GEN_*2);
  us* agzr  = (us*)alloc((size_t)B_*CON_*2);
  us* achh  = (us*)alloc((size_t)B_*416*2);
  us* aghh  = (us*)alloc((size_t)B_*GEN_*2);
  float* zcon  = (float*)alloc((size_t)B_*CON_*4);
  float* xhcon = (float*)alloc((size_t)B_*CON_*4);
  float* zgen  = (float*)alloc((size_t)B_*GEN_*4);
  float* xhgen = (float*)alloc((size_t)B_*GEN_*4);
  us* cib  = (us*)alloc((size_t)B_*T_*CI_*2);
  us* extb = (us*)alloc((size_t)B_*T_*EXT_*2);
  us* zbuf = (us*)alloc(64UL*2);
  unsigned* gsync = (unsigned*)alloc((size_t)GSYNC_N*4);
  (void)ws_size; (void)in_sizes; (void)n_in; (void)out_size;

  dim3 blk(256);
  k_facnorm<<<dim3(128), dim3(64), 0, stream>>>(facW, facWn);
  k_w2<<<dim3(5, 800), blk, 0, stream>>>(facWn, conK, tmp2);
  k_w1<<<dim3(10, 400), blk, 0, stream>>>(comW, genK, tmp1);
  k_cvt<<<dim3(1024), blk, 0, stream>>>(ci, ext, cib, extb);
  k_init<<<dim3(2048), blk, 0, stream>>>(conh0, geninit, conb, genb, comb, genK,
                                         bczr, bgzr, conh, agzr, genh, genhb, achh,
                                         zbuf, gsync);

  BTArgs bt;
  bt.conK = conK; bt.conR = conR; bt.genK = genK; bt.genR = genR;
  bt.facWn = facWn; bt.tmp1 = tmp1; bt.tmp2 = tmp2;
  bt.mode = 0; bt.K = 1344; bt.dst = wczr; k_buildT<<<dim3(21,22), blk, 0, stream>>>(bt);
  bt.mode = 1; bt.K = 416;  bt.dst = wchh; k_buildT<<<dim3(7,8),   blk, 0, stream>>>(bt);
  bt.mode = 2; bt.K = 1216; bt.dst = wgzr; k_buildT<<<dim3(19,38), blk, 0, stream>>>(bt);
  bt.mode = 3; bt.K = 800;  bt.dst = wghh; k_buildT<<<dim3(13,14), blk, 0, stream>>>(bt);
  bt.mode = 4; bt.K = 800;  bt.dst = wfac; k_buildT<<<dim3(13,3),  blk, 0, stream>>>(bt);

  PA pa;
  pa.cib = cib; pa.extb = extb;
  pa.wczr = wczr; pa.wchh = wchh; pa.wgzr = wgzr; pa.wghh = wghh; pa.wfac = wfac;
  pa.bczr = bczr; pa.bgzr = bgzr;
  pa.zcon = zcon; pa.xhcon = xhcon; pa.zgen = zgen; pa.xhgen = xhgen;
  pa.conh = conh; pa.genh = genh;
  pa.genhb = genhb; pa.agzr = agzr; pa.achh = achh; pa.aghh = aghh;
  pa.zbuf = zbuf; pa.out = out; pa.gs = gsync;

  decoder_persist<<<dim3(NBLK), blk, 0, stream>>>(pa);
}

// Round 10
// 13292.429 us; speedup vs baseline: 1.8447x; 1.8447x over previous
//
#include <hip/hip_runtime.h>
#include <cstdint>
#include <cstddef>

// Decoder (LFADS-like): B=512, T=200.
// Persistent kernel v5 — per-XCD islands (r8-proven sync) + DEEP-PIPELINED
// LDS staging:
//   * r8/r9 were fill-LATENCY-bound (~1KB effectively in flight per block;
//     compiler recycled load buffers at VGPR=72). v5 stages via
//     global_load_lds (no VGPR cost): per 128-K chunk each wave issues
//     8x1KB, double-buffered with counted `s_waitcnt vmcnt(8)` -> 8-16KB in
//     flight PER WAVE.
//   * LDS XOR-swizzle (block ^= row&7 on 16B blocks) -> conflict-free
//     ds_read_b128; swizzle applied on the per-lane GLOBAL source (m173).
//   * zero-pad K-tails skipped: GZR xh-cols K 1216->416, CZR xh/fac-cols
//     42->29 kt (−15% fill traffic).
//   * NBLK=256 (32 blocks/XCD, r8's best). Sync = r8/r9 sc0-atomic barriers.
// Precomposed weights: W' = com_W@gen_K[:32]; W'' = fac_Wn@con_K[128:].

#define B_   512
#define T_   200
#define CI_  128
#define EXT_ 8
#define GEN_ 800
#define CON_ 400
#define CO_  32
#define FAC_ 128
#define NBLK 256

typedef __attribute__((ext_vector_type(8))) short short8;
typedef __attribute__((ext_vector_type(4))) float f32x4;
typedef __attribute__((ext_vector_type(4))) unsigned short us4;
typedef unsigned short us;

typedef __attribute__((address_space(1))) void as1v;
typedef __attribute__((address_space(3))) void as3v;

// sync-cell layout in gs (u32 indices, 256 B apart => one XCD per line):
#define ARR_(g,c) (((g)*4+(c))*64)
#define FLAG_(g)  (2048 + (g)*64)
#define ROOT_(g)  (2560 + (g)*64)
#define SLOT_(g)  (3584 + (g)*64)
#define AREG_     4096
#define GSYNC_N   4352

__device__ __forceinline__ us f2bf(float f) {
  unsigned int u = __float_as_uint(f);
  u += 0x7FFFu + ((u >> 16) & 1u);   // RNE
  return (us)(u >> 16);
}
__device__ __forceinline__ unsigned pk2(float a, float b) {
  return (unsigned)f2bf(a) | ((unsigned)f2bf(b) << 16);
}
__device__ __forceinline__ float sigm(float x) { return 1.0f / (1.0f + __expf(-x)); }

__device__ __forceinline__ void gload16(const void* g, void* l) {
  __builtin_amdgcn_global_load_lds((as1v*)g, (as3v*)l, 16, 0, 0);
}

// ---- sc0 (XCD-L2-coherent) primitives -------------------------------------
__device__ __forceinline__ void st128_sc0(void* p, f32x4 v) {
  asm volatile("global_store_dwordx4 %0, %1, off sc0" :: "v"(p), "v"(v) : "memory");
}
__device__ __forceinline__ void st64_sc0(void* p, unsigned lo, unsigned hi) {
  unsigned long long v = (unsigned long long)lo | ((unsigned long long)hi << 32);
  asm volatile("global_store_dwordx2 %0, %1, off sc0" :: "v"(p), "v"(v) : "memory");
}
__device__ __forceinline__ void st32_sc0(void* p, unsigned v) {
  asm volatile("global_store_dword %0, %1, off sc0" :: "v"(p), "v"(v) : "memory");
}
__device__ __forceinline__ unsigned atom_add_sc0(void* p, unsigned d) {
  unsigned old;
  asm volatile("global_atomic_add %0, %1, %2, off sc0\n\ts_waitcnt vmcnt(0)"
               : "=v"(old) : "v"(p), "v"(d) : "memory");
  return old;
}
__device__ __forceinline__ unsigned ld_l2(void* p) { return atom_add_sc0(p, 0u); }

// ---------------- setup kernels ----------------

__global__ void k_facnorm(const float* __restrict__ facW, float* __restrict__ facWn) {
  int j = blockIdx.x;
  int l = threadIdx.x;
  float s = 0.f;
  for (int k = l; k < GEN_; k += 64) { float v = facW[(size_t)k*FAC_ + j]; s += v*v; }
  #pragma unroll
  for (int off = 32; off > 0; off >>= 1) s += __shfl_down(s, off, 64);
  float inv = 1.0f / sqrtf(__shfl(s, 0, 64));
  for (int k = l; k < GEN_; k += 64) facWn[(size_t)k*FAC_ + j] = facW[(size_t)k*FAC_ + j] * inv;
}

__global__ void k_w2(const float* __restrict__ facWn, const float* __restrict__ conK,
                     float* __restrict__ tmp2) {
  int n = blockIdx.x*256 + threadIdx.x; if (n >= 1200) return;
  int kp = blockIdx.y;
  const float* fr = facWn + (size_t)kp*FAC_;
  float s = 0.f;
  for (int j = 0; j < FAC_; ++j) s = fmaf(fr[j], conK[(size_t)(CI_+j)*1200 + n], s);
  tmp2[(size_t)kp*1200 + n] = s;
}

__global__ void k_w1(const float* __restrict__ comW, const float* __restrict__ genK,
                     float* __restrict__ tmp1) {
  int n = blockIdx.x*256 + threadIdx.x; if (n >= 2400) return;
  int k = blockIdx.y;
  const float* cr = comW + (size_t)k*CO_;
  float s = 0.f;
  for (int j = 0; j < CO_; ++j) s = fmaf(cr[j], genK[(size_t)j*2400 + n], s);
  tmp1[(size_t)k*2400 + n] = s;
}

__global__ void k_cvt(const float* __restrict__ ci, const float* __restrict__ ext,
                      us* __restrict__ cib, us* __restrict__ extb) {
  const long n1 = (long)B_*T_*CI_/4;
  const long n2 = (long)B_*T_*EXT_/4;
  for (long i = blockIdx.x*(long)blockDim.x + threadIdx.x; i < n1+n2;
       i += (long)gridDim.x*blockDim.x) {
    if (i < n1) {
      float4 f = reinterpret_cast<const float4*>(ci)[i];
      us4 u; u.x=f2bf(f.x); u.y=f2bf(f.y); u.z=f2bf(f.z); u.w=f2bf(f.w);
      reinterpret_cast<us4*>(cib)[i] = u;
    } else {
      long k = i - n1;
      float4 f = reinterpret_cast<const float4*>(ext)[k];
      us4 u; u.x=f2bf(f.x); u.y=f2bf(f.y); u.z=f2bf(f.z); u.w=f2bf(f.w);
      reinterpret_cast<us4*>(extb)[k] = u;
    }
  }
}

__global__ void k_init(const float* __restrict__ conh0, const float* __restrict__ geninit,
                       const float* __restrict__ conb, const float* __restrict__ genb,
                       const float* __restrict__ comb, const float* __restrict__ genK,
                       float* __restrict__ bczr, float* __restrict__ bgzr,
                       float* __restrict__ conh, us* __restrict__ agzr,
                       float* __restrict__ genh, us* __restrict__ genhb,
                       us* __restrict__ achh,
                       us* __restrict__ zbuf, unsigned* __restrict__ gs) {
  const long R0=1344, R1=2432, R2=(long)B_*CON_, R3=(long)B_*CON_,
             R4=(long)B_*GEN_, R5=(long)B_*GEN_, R6=(long)B_*416, R7=64, R8=GSYNC_N;
  const long total = R0+R1+R2+R3+R4+R5+R6+R7+R8;
  for (long idx = blockIdx.x*(long)blockDim.x + threadIdx.x; idx < total;
       idx += (long)gridDim.x*blockDim.x) {
    long i = idx;
    if (i < R0) { bczr[i] = (i < 1200) ? conb[i] : 0.f; continue; }
    i -= R0;
    if (i < R1) {
      float s = 0.f;
      if (i < 2400) { s = genb[i]; for (int j=0;j<32;++j) s = fmaf(comb[j], genK[(size_t)j*2400 + i], s); }
      bgzr[i] = s; continue;
    }
    i -= R1;
    if (i < R2) { conh[i] = conh0[i % CON_]; continue; }
    i -= R2;
    if (i < R3) { agzr[i] = f2bf(conh0[i % CON_]); continue; }
    i -= R3;
    if (i < R4) { genh[i] = geninit[i]; continue; }
    i -= R4;
    if (i < R5) { genhb[i] = f2bf(geninit[i]); continue; }
    i -= R5;
    if (i < R6) { achh[i] = 0; continue; }
    i -= R6;
    if (i < R7) { zbuf[i] = 0; continue; }
    i -= R7;
    gs[i] = 0;
  }
}

// build transposed bf16 weights: dst[n][k] = fetch(k, n)
struct BTArgs {
  int mode, K;
  const float* conK; const float* conR; const float* genK; const float* genR;
  const float* facWn; const float* tmp1; const float* tmp2;
  us* dst;
};

__device__ __forceinline__ float bt_fetch(const BTArgs& a, int k, int n) {
  switch (a.mode) {
    case 0: // W_czr^T
      if (n < 1200) {
        if (k < 128)  return a.conK[(size_t)k*1200 + n];
        if (k < 928)  return a.tmp2[(size_t)(k-128)*1200 + n];
        if (k < 1328) return (n < 800) ? a.conR[(size_t)(k-928)*1200 + n] : 0.f;
        return 0.f;
      }
      if (n < 1328) return (k >= 128 && k < 928) ? a.facWn[(size_t)(k-128)*FAC_ + (n-1200)] : 0.f;
      return 0.f;
    case 1: // W_chh^T
      return (k < 400 && n < 400) ? a.conR[(size_t)k*1200 + 800 + n] : 0.f;
    case 2: // W_gzr^T
      if (n >= 2400) return 0.f;
      if (k < 400)  return a.tmp1[(size_t)k*2400 + n];
      if (k < 408)  return a.genK[(size_t)(32 + k - 400)*2400 + n];
      if (k < 416)  return 0.f;
      if (k < 1216) return (n < 1600) ? a.genR[(size_t)(k-416)*2400 + n] : 0.f;
      return 0.f;
    case 3: // W_ghh^T
      return (n < 800 && k < 800) ? a.genR[(size_t)k*2400 + 1600 + n] : 0.f;
    default: // fac_Wn^T
      return (k < 800 && n < 128) ? a.facWn[(size_t)k*FAC_ + n] : 0.f;
  }
}

__global__ __launch_bounds__(256) void k_buildT(BTArgs a) {
  __shared__ float tile[64][65];
  int k0 = blockIdx.x*64, n0 = blockIdx.y*64;
  int tid = threadIdx.x;
  int rr = tid >> 2, cc = (tid & 3) * 16;
  #pragma unroll 4
  for (int i = 0; i < 16; ++i) tile[rr][cc+i] = bt_fetch(a, k0+rr, n0+cc+i);
  __syncthreads();
  int n = n0 + rr;
  if (k0 + cc < a.K) {
    short8 v0, v1;
    #pragma unroll
    for (int i = 0; i < 8; ++i) v0[i] = (short)f2bf(tile[cc+i][rr]);
    #pragma unroll
    for (int i = 0; i < 8; ++i) v1[i] = (short)f2bf(tile[cc+8+i][rr]);
    *reinterpret_cast<short8*>(&a.dst[(size_t)n*a.K + k0 + cc])     = v0;
    *reinterpret_cast<short8*>(&a.dst[(size_t)n*a.K + k0 + cc + 8]) = v1;
  }
}

// ---------------- persistent decoder ----------------

struct PA {
  const us* cib; const us* extb;
  const us* wczr; const us* wchh; const us* wgzr; const us* wghh; const us* wfac;
  const float* bczr; const float* bgzr;
  float* zcon; float* xhcon; float* zgen; float* xhgen;
  float* conh; float* genh;
  us* genhb; us* agzr; us* achh; us* aghh;
  const us* zbuf;
  float* out;
  unsigned* gs;
};

enum { S_CZR=0, S_CHH=1, S_GZR=2, S_GHH=3, S_FAC=4 };

__device__ __forceinline__ void gbar(unsigned* gs, int g, int slot, unsigned cnt, unsigned ep) {
  asm volatile("s_waitcnt vmcnt(0)" ::: "memory");
  __syncthreads();
  if (threadIdx.x == 0) {
    const unsigned c = (unsigned)slot & 3u;
    const unsigned n_c = (cnt + 3u - c) >> 2;
    unsigned old = atom_add_sc0(&gs[ARR_(g, c)], 1u);
    if (old + 1u >= n_c * ep) {
      const unsigned nsub = cnt < 4u ? cnt : 4u;
      unsigned r = atom_add_sc0(&gs[ROOT_(g)], 1u);
      if (r + 1u >= nsub * ep) st32_sc0(&gs[FLAG_(g)], ep);
    }
    long guard = 0;
    for (;;) {
      unsigned v = ld_l2(&gs[FLAG_(g)]);
      if ((int)(v - ep) >= 0) break;
      if (++guard > 300000L) break;
      __builtin_amdgcn_s_sleep(1);
    }
  }
  __syncthreads();
  asm volatile("buffer_inv sc0" ::: "memory");
}

template<int STAGE>
__device__ __forceinline__ void epi(const PA& a, int t, int bb, int c0, f32x4 v) {
  if constexpr (STAGE == S_CZR) {
    if (c0 < 400) {
      float4 b = *reinterpret_cast<const float4*>(&a.bczr[c0]);
      f32x4 z = { sigm(v[0]+b.x), sigm(v[1]+b.y), sigm(v[2]+b.z), sigm(v[3]+b.w) };
      st128_sc0(&a.zcon[(size_t)bb*CON_ + c0], z);
    } else if (c0 < 800) {
      float4 b = *reinterpret_cast<const float4*>(&a.bczr[c0]);
      int u0 = c0 - 400;
      float4 hp = *reinterpret_cast<const float4*>(&a.conh[(size_t)bb*CON_ + u0]);
      float r0 = sigm(v[0]+b.x)*hp.x, r1 = sigm(v[1]+b.y)*hp.y;
      float r2 = sigm(v[2]+b.z)*hp.z, r3 = sigm(v[3]+b.w)*hp.w;
      st64_sc0(&a.achh[(size_t)bb*416 + u0], pk2(r0,r1), pk2(r2,r3));
    } else if (c0 < 1200) {
      float4 b = *reinterpret_cast<const float4*>(&a.bczr[c0]);
      f32x4 x = { v[0]+b.x, v[1]+b.y, v[2]+b.z, v[3]+b.w };
      st128_sc0(&a.xhcon[(size_t)bb*CON_ + (c0-800)], x);
    } else if (c0 < 1328) {
      if (t > 0) {
        float4* o = reinterpret_cast<float4*>(&a.out[((size_t)bb*T_ + (t-1))*FAC_ + (c0-1200)]);
        *o = make_float4(v[0], v[1], v[2], v[3]);
      }
    }
  } else if constexpr (STAGE == S_CHH) {
    if (c0 < 400) {
      float4 xh = *reinterpret_cast<const float4*>(&a.xhcon[(size_t)bb*CON_ + c0]);
      float4 zz = *reinterpret_cast<const float4*>(&a.zcon [(size_t)bb*CON_ + c0]);
      float4 hp = *reinterpret_cast<const float4*>(&a.conh [(size_t)bb*CON_ + c0]);
      float h[4]; float xs[4] = {xh.x,xh.y,xh.z,xh.w};
      float zs[4] = {zz.x,zz.y,zz.z,zz.w}; float hs[4] = {hp.x,hp.y,hp.z,hp.w};
      #pragma unroll
      for (int j=0;j<4;++j) {
        float hh = tanhf(v[j] + xs[j]);
        float hn = zs[j]*hs[j] + (1.f - zs[j])*hh;
        h[j] = fminf(fmaxf(hn, -5.f), 5.f);
      }
      st128_sc0(&a.conh[(size_t)bb*CON_ + c0], (f32x4){h[0],h[1],h[2],h[3]});
      st64_sc0(&a.agzr[(size_t)bb*CON_ + c0], pk2(h[0],h[1]), pk2(h[2],h[3]));
    }
  } else if constexpr (STAGE == S_GZR) {
    if (c0 < 800) {
      float4 b = *reinterpret_cast<const float4*>(&a.bgzr[c0]);
      f32x4 z = { sigm(v[0]+b.x), sigm(v[1]+b.y), sigm(v[2]+b.z), sigm(v[3]+b.w) };
      st128_sc0(&a.zgen[(size_t)bb*GEN_ + c0], z);
    } else if (c0 < 1600) {
      float4 b = *reinterpret_cast<const float4*>(&a.bgzr[c0]);
      int u0 = c0 - 800;
      float4 hp = *reinterpret_cast<const float4*>(&a.genh[(size_t)bb*GEN_ + u0]);
      float r0 = sigm(v[0]+b.x)*hp.x, r1 = sigm(v[1]+b.y)*hp.y;
      float r2 = sigm(v[2]+b.z)*hp.z, r3 = sigm(v[3]+b.w)*hp.w;
      st64_sc0(&a.aghh[(size_t)bb*GEN_ + u0], pk2(r0,r1), pk2(r2,r3));
    } else if (c0 < 2400) {
      float4 b = *reinterpret_cast<const float4*>(&a.bgzr[c0]);
      f32x4 x = { v[0]+b.x, v[1]+b.y, v[2]+b.z, v[3]+b.w };
      st128_sc0(&a.xhgen[(size_t)bb*GEN_ + (c0-1600)], x);
    }
  } else if constexpr (STAGE == S_GHH) {
    if (c0 < 800) {
      float4 xh = *reinterpret_cast<const float4*>(&a.xhgen[(size_t)bb*GEN_ + c0]);
      float4 zz = *reinterpret_cast<const float4*>(&a.zgen [(size_t)bb*GEN_ + c0]);
      float4 hp = *reinterpret_cast<const float4*>(&a.genh [(size_t)bb*GEN_ + c0]);
      float h[4]; float xs[4] = {xh.x,xh.y,xh.z,xh.w};
      float zs[4] = {zz.x,zz.y,zz.z,zz.w}; float hs[4] = {hp.x,hp.y,hp.z,hp.w};
      #pragma unroll
      for (int j=0;j<4;++j) {
        float hh = tanhf(v[j] + xs[j]);
        float hn = zs[j]*hs[j] + (1.f - zs[j])*hh;
        h[j] = fminf(fmaxf(hn, -5.f), 5.f);
      }
      st128_sc0(&a.genh[(size_t)bb*GEN_ + c0], (f32x4){h[0],h[1],h[2],h[3]});
      st64_sc0(&a.genhb[(size_t)bb*GEN_ + c0], pk2(h[0],h[1]), pk2(h[2],h[3]));
    }
  } else { // S_FAC
    if (c0 < 128) {
      float4* o = reinterpret_cast<float4*>(&a.out[((size_t)bb*T_ + (T_-1))*FAC_ + c0]);
      *o = make_float4(v[0], v[1], v[2], v[3]);
    }
  }
}

// LDS tiles: lA[buf][row 0..63][k 0..127] bf16 (256B rows, XOR-swizzled 16B
// blocks); lB[buf][frag 0..3][n 0..15][k 0..127].
typedef us ldsA_t[2][64][128];
typedef us ldsB_t[2][4][16][128];

// KT_END: valid kt count (skip zero K-tails); FOFF/FCNT: frag sub-range.
template<int STAGE, int K, int KT_END, int FOFF, int FCNT>
__device__ __forceinline__ void do_stage(const PA& a, int t, int g, int slot, int cnt,
                                         ldsA_t& lA, ldsB_t& lB) {
  constexpr int CHUNKS = (KT_END + 3) / 4;
  const int lane = threadIdx.x & 63, wid = threadIdx.x >> 6;
  int base = (int)((long)slot * FCNT / cnt);
  int end  = (int)((long)(slot+1) * FCNT / cnt);
  if (end > FCNT) end = FCNT;
  if (base >= end) return;
  base += FOFF; end += FOFF;

  const us* warr =
      STAGE == S_CZR ? a.wczr : STAGE == S_CHH ? a.wchh :
      STAGE == S_GZR ? a.wgzr : STAGE == S_GHH ? a.wghh : a.wfac;

  const int l15 = lane & 15, ko = lane >> 4;
  const int bb = g*64 + wid*16 + l15;      // this lane's batch row (epi/compute)

  for (int fg = base; fg < end; fg += 4) {
    f32x4 acc[4];
    #pragma unroll
    for (int j = 0; j < 4; ++j) acc[j] = (f32x4){0.f,0.f,0.f,0.f};

    const int fmine = (fg + wid < end) ? (fg + wid) : fg;   // frag staged by this wave

    auto stage = [&](int buf, int kc) {
      // A: own 16 rows, 4 issues (1KB each = 4 rows x 256B)
      #pragma unroll
      for (int j = 0; j < 4; ++j) {
        const int r  = wid*16 + j*4 + (lane >> 4);
        const size_t rb = (size_t)(g*64 + r);
        const int lb = (lane & 15) ^ (r & 7);
        const int k0 = kc*128 + lb*8;
        const us* p;
        if constexpr (STAGE == S_CZR) {
          p = k0 < 128 ? a.cib + (rb*T_ + t)*CI_ + k0
            : k0 < 928 ? a.genhb + rb*GEN_ + (k0-128)
            : k0 < 1328 ? a.agzr + rb*CON_ + (k0-928) : a.zbuf;
        } else if constexpr (STAGE == S_CHH) {
          p = k0 < 416 ? a.achh + rb*416 + k0 : a.zbuf;
        } else if constexpr (STAGE == S_GZR) {
          p = k0 < 400 ? a.agzr + rb*CON_ + k0
            : k0 < 408 ? a.extb + (rb*T_ + t)*EXT_
            : k0 < 416 ? a.zbuf
            : k0 < 1216 ? a.genhb + rb*GEN_ + (k0-416) : a.zbuf;
        } else if constexpr (STAGE == S_GHH) {
          p = k0 < 800 ? a.aghh + rb*GEN_ + k0 : a.zbuf;
        } else {
          p = k0 < 800 ? a.genhb + rb*GEN_ + k0 : a.zbuf;
        }
        gload16(p, &lA[buf][wid*16 + j*4][0]);
      }
      // B: this wave's frag, 4 issues
      #pragma unroll
      for (int jj = 0; jj < 4; ++jj) {
        const int nl = jj*4 + (lane >> 4);
        const int ng = fmine*16 + nl;
        const int lb = (lane & 15) ^ (nl & 7);
        const int k0 = kc*128 + lb*8;
        gload16(warr + (size_t)ng*K + k0, &lB[buf][wid][jj*4][0]);
      }
    };

    stage(0, 0);
    for (int kc = 0; kc < CHUNKS; ++kc) {
      const int cur = kc & 1;
      if (kc + 1 < CHUNKS) {
        stage(cur ^ 1, kc + 1);
        asm volatile("s_waitcnt vmcnt(8)" ::: "memory");
      } else {
        asm volatile("s_waitcnt vmcnt(0)" ::: "memory");
      }
      __builtin_amdgcn_s_barrier();
      const int ktlo = kc*4;
      const int kthi = (ktlo + 4 < KT_END) ? ktlo + 4 : KT_END;
      const int arow = wid*16 + l15;
      for (int kt = ktlo; kt < kthi; ++kt) {
        const int boff = (((kt - ktlo)*4 + ko) ^ (l15 & 7)) * 8;
        short8 av = *reinterpret_cast<const short8*>(&lA[cur][arow][boff]);
        #pragma unroll
        for (int j = 0; j < 4; ++j) {
          if (fg + j < end) {
            short8 bv = *reinterpret_cast<const short8*>(&lB[cur][j][l15][boff]);
            acc[j] = __builtin_amdgcn_mfma_f32_16x16x32_bf16(bv, av, acc[j], 0,0,0);
          }
        }
      }
      __builtin_amdgcn_s_barrier();
    }

    const int cq = ko * 4;
    #pragma unroll
    for (int j = 0; j < 4; ++j)
      if (fg + j < end) epi<STAGE>(a, t, bb, (fg+j)*16 + cq, acc[j]);
  }
}

__global__ __launch_bounds__(256) void decoder_persist(PA a) {
  __shared__ us lA[2][64][128];
  __shared__ us lB[2][4][16][128];
  const int tid = threadIdx.x;
  unsigned xcc;
  asm("s_getreg_b32 %0, hwreg(HW_REG_XCC_ID)" : "=s"(xcc));
  const int g = (int)(xcc & 7u);

  __shared__ int s_slot, s_cnt;
  if (tid == 0) {
    s_slot = (int)atom_add_sc0(&a.gs[SLOT_(g)], 1u);
  }
  __syncthreads();
  if (tid == 0) {
    __hip_atomic_fetch_add(&a.gs[AREG_], 1u, __ATOMIC_RELAXED, __HIP_MEMORY_SCOPE_AGENT);
    long guard = 0;
    for (;;) {
      unsigned v = __hip_atomic_load(&a.gs[AREG_], __ATOMIC_RELAXED, __HIP_MEMORY_SCOPE_AGENT);
      if (v >= (unsigned)NBLK) break;
      if (++guard > 20000000L) break;
      __builtin_amdgcn_s_sleep(1);
    }
    int c = (int)ld_l2(&a.gs[SLOT_(g)]);
    s_cnt = c < 1 ? 1 : c;
  }
  __syncthreads();
  const int slot = s_slot;
  const unsigned cnt = (unsigned)s_cnt;
  asm volatile("buffer_inv sc0" ::: "memory");

  unsigned ep = 0;
  for (int t = 0; t < T_; ++t) {
    do_stage<S_CZR, 1344, 42,  0,  50>(a, t, g, slot, (int)cnt, lA, lB);  // z,r,r*h cols
    do_stage<S_CZR, 1344, 29, 50,  33>(a, t, g, slot, (int)cnt, lA, lB);  // xh+fac cols (K-tail zero)
    gbar(a.gs, g, slot, cnt, ++ep);
    do_stage<S_CHH,  416, 13,  0,  25>(a, t, g, slot, (int)cnt, lA, lB);
    gbar(a.gs, g, slot, cnt, ++ep);
    do_stage<S_GZR, 1216, 38,  0, 100>(a, t, g, slot, (int)cnt, lA, lB);  // z,r cols
    do_stage<S_GZR, 1216, 13, 100,  50>(a, t, g, slot, (int)cnt, lA, lB); // xh cols (K-tail zero)
    gbar(a.gs, g, slot, cnt, ++ep);
    do_stage<S_GHH,  800, 25,  0,  50>(a, t, g, slot, (int)cnt, lA, lB);
    gbar(a.gs, g, slot, cnt, ++ep);
  }
  do_stage<S_FAC, 800, 25, 0, 8>(a, T_-1, g, slot, (int)cnt, lA, lB);
}

// ---------------- host ----------------

extern "C" void kernel_launch(void* const* d_in, const int* in_sizes, int n_in,
                              void* d_out, int out_size, void* d_ws, size_t ws_size,
                              hipStream_t stream) {
  const float* ci      = (const float*)d_in[0];
  const float* ext     = (const float*)d_in[1];
  const float* geninit = (const float*)d_in[2];
  const float* conh0   = (const float*)d_in[3];
  const float* conK    = (const float*)d_in[4];
  const float* conR    = (const float*)d_in[5];
  const float* conb    = (const float*)d_in[6];
  const float* comW    = (const float*)d_in[7];
  const float* comb    = (const float*)d_in[8];
  const float* genK    = (const float*)d_in[11];
  const float* genR    = (const float*)d_in[12];
  const float* genb    = (const float*)d_in[13];
  const float* facW    = (const float*)d_in[14];
  float* out = (float*)d_out;

  char* ws = (char*)d_ws;
  size_t off = 0;
  auto alloc = [&](size_t bytes) -> void* {
    void* p = ws + off;
    off = (off + bytes + 255) & ~(size_t)255;
    return p;
  };
  us* wczr  = (us*)alloc(1408UL*1344*2);
  us* wchh  = (us*)alloc(512UL*416*2);
  us* wgzr  = (us*)alloc(2432UL*1216*2);
  us* wghh  = (us*)alloc(896UL*800*2);
  us* wfac  = (us*)alloc(192UL*800*2);
  float* facWn = (float*)alloc(800UL*128*4);
  float* tmp2  = (float*)alloc(800UL*1200*4);
  float* tmp1  = (float*)alloc(400UL*2400*4);
  float* bczr  = (float*)alloc(1344UL*4);
  float* bgzr  = (float*)alloc(2432UL*4);
  float* conh  = (float*)alloc((size_t)B_*CON_*4);
  float* genh  = (float*)alloc((size_t)B_*GEN_*4);
  us* genhb = (us*)alloc((size_t)B_*GEN_*2);
  us* agzr  = (us*)alloc((size_t)B_*CON_*2);
  us* achh  = (us*)alloc((size_t)B_*416*2);
  us* aghh  = (us*)alloc((size_t)B_*GEN_*2);
  float* zcon  = (float*)alloc((size_t)B_*CON_*4);
  float* xhcon = (float*)alloc((size_t)B_*CON_*4);
  float* zgen  = (float*)alloc((size_t)B_*GEN_*4);
  float* xhgen = (float*)alloc((size_t)B_*GEN_*4);
  us* cib  = (us*)alloc((size_t)B_*T_*CI_*2);
  us* extb = (us*)alloc((size_t)B_*T_*EXT_*2);
  us* zbuf = (us*)alloc(256UL*2);
  unsigned* gsync = (unsigned*)alloc((size_t)GSYNC_N*4);
  (void)ws_size; (void)in_sizes; (void)n_in; (void)out_size;

  dim3 blk(256);
  k_facnorm<<<dim3(128), dim3(64), 0, stream>>>(facW, facWn);
  k_w2<<<dim3(5, 800), blk, 0, stream>>>(facWn, conK, tmp2);
  k_w1<<<dim3(10, 400), blk, 0, stream>>>(comW, genK, tmp1);
  k_cvt<<<dim3(1024), blk, 0, stream>>>(ci, ext, cib, extb);
  k_init<<<dim3(2048), blk, 0, stream>>>(conh0, geninit, conb, genb, comb, genK,
                                         bczr, bgzr, conh, agzr, genh, genhb, achh,
                                         zbuf, gsync);

  BTArgs bt;
  bt.conK = conK; bt.conR = conR; bt.genK = genK; bt.genR = genR;
  bt.facWn = facWn; bt.tmp1 = tmp1; bt.tmp2 = tmp2;
  bt.mode = 0; bt.K = 1344; bt.dst = wczr; k_buildT<<<dim3(21,22), blk, 0, stream>>>(bt);
  bt.mode = 1; bt.K = 416;  bt.dst = wchh; k_buildT<<<dim3(7,8),   blk, 0, stream>>>(bt);
  bt.mode = 2; bt.K = 1216; bt.dst = wgzr; k_buildT<<<dim3(19,38), blk, 0, stream>>>(bt);
  bt.mode = 3; bt.K = 800;  bt.dst = wghh; k_buildT<<<dim3(13,14), blk, 0, stream>>>(bt);
  bt.mode = 4; bt.K = 800;  bt.dst = wfac; k_buildT<<<dim3(13,3),  blk, 0, stream>>>(bt);

  PA pa;
  pa.cib = cib; pa.extb = extb;
  pa.wczr = wczr; pa.wchh = wchh; pa.wgzr = wgzr; pa.wghh = wghh; pa.wfac = wfac;
  pa.bczr = bczr; pa.bgzr = bgzr;
  pa.zcon = zcon; pa.xhcon = xhcon; pa.zgen = zgen; pa.xhgen = xhgen;
  pa.conh = conh; pa.genh = genh;
  pa.genhb = genhb; pa.agzr = agzr; pa.achh = achh; pa.aghh = aghh;
  pa.zbuf = zbuf; pa.out = out; pa.gs = gsync;

  decoder_persist<<<dim3(NBLK), blk, 0, stream>>>(pa);
}